// Round 5
// baseline (54.389 us; speedup 1.0000x reference)
//
#include <hip/hip_runtime.h>

// RoiAlign: fm (4,256,50,50) f32, boxes (512,4), box_idx (512) -> out (512,256,14,14) f32
//
// R4b: minimize vector-memory INSTRUCTION count (TA processes ~4 addr/cy ->
// every wave64 vector-mem op costs ~16cy regardless of width).
//  - Phase A: stage the box's 16x16 window per plane with dwordx2 loads
//    (even-aligned window origin xE) + ds_write_b64.
//  - Window is clamp-duplicated (gy=min(yLo+r,49), pair-start min(...,48)), so
//    the 4 bilinear taps live at w00+{0,1,WC,WC+1} -> 2x ds_read2_b32/elem.
//  - Phase B: thread owns a QUAD of 4 consecutive output positions -> one
//    nontemporal global_store_dwordx4 per 4 elements (native ext_vector f32x4;
//    HIP float4 is a class type the builtin rejects). Coord math once/thread.
// XCD affinity: all 8 chunks of a box on one XCD (bid%8 partition).

typedef float f32x4 __attribute__((ext_vector_type(4)));
typedef float f32x2 __attribute__((ext_vector_type(2)));

constexpr int C_DIM = 256;
constexpr int H_DIM = 50;
constexpr int W_DIM = 50;
constexpr int M_BOX = 512;
constexpr int CW    = 14;
constexpr int NPOS  = 196;            // 14*14
constexpr int CCH   = 32;             // channels per block
constexpr int NCHUNK = C_DIM / CCH;   // 8
constexpr int PLANE  = H_DIM * W_DIM; // 2500
constexpr int WC  = 16;               // window cols
constexpr int WSZ = 256;              // 16 rows x 16 cols per plane
constexpr float INV_STRIDE = 1.0f / 16.0f;

__global__ __launch_bounds__(256) void roi_align_v4(
    const float* __restrict__ fm,
    const float* __restrict__ boxes,
    const int*   __restrict__ box_idx,
    float*       __restrict__ out)
{
    __shared__ float Wnd[CCH * WSZ];  // 32 KB

    int bid     = blockIdx.x;
    int logical = (bid & 7) * ((M_BOX * NCHUNK) / 8) + (bid >> 3);
    int m       = logical >> 3;
    int cbase   = (logical & 7) * CCH;

    int t = threadIdx.x;

    float4 bx = reinterpret_cast<const float4*>(boxes)[m];
    int bi = box_idx[m];
    float x1 = bx.x * INV_STRIDE;
    float y1 = bx.y * INV_STRIDE;
    float x2 = bx.z * INV_STRIDE;
    float y2 = bx.w * INV_STRIDE;

    // Window origin; x origin even so dwordx2 pairs are 8B aligned.
    int xLo = min(max((int)floorf(x1), 0), W_DIM - 1);
    int yLo = min(max((int)floorf(y1), 0), H_DIM - 1);
    int xE  = xLo & ~1;

    // ---- Phase A: stage 16x16 window of each of CCH planes ----
    {
        int sub = t & 7;          // x2-pair: cols sub*2, sub*2+1
        int rr  = (t >> 3) & 15;  // window row 0..15
        int pg  = t >> 7;         // plane parity 0/1
        int gy  = min(yLo + rr, H_DIM - 1);          // row clamp-duplicate
        int gxp = min(xE + sub * 2, W_DIM - 2);      // pair start <= 48
        const float* gsrc = fm + ((size_t)(bi * C_DIM + cbase + pg)) * PLANE
                               + gy * W_DIM + gxp;
        float* ldst = &Wnd[pg * WSZ + rr * WC + sub * 2];
        #pragma unroll
        for (int k = 0; k < CCH / 2; ++k) {
            f32x2 v = *reinterpret_cast<const f32x2*>(gsrc);
            *reinterpret_cast<f32x2*>(ldst) = v;
            gsrc += 2 * (size_t)PLANE;
            ldst += 2 * WSZ;
        }
    }
    __syncthreads();

    // ---- Phase B: one thread = one output quad (4 consecutive positions) ----
    if (t < NPOS) {
        int csub = t / 49;        // 0..3 -> channels csub*8 .. csub*8+7
        int q    = t - csub * 49; // quad 0..48 -> positions 4q..4q+3

        int   w00[4];
        float wxv[4], owx[4], wyv[4], owy[4];
        bool  vld[4];
        #pragma unroll
        for (int e = 0; e < 4; ++e) {
            int p  = 4 * q + e;
            int iy = p / CW;
            int ix = p - iy * CW;
            // reference op order: v1 + (i * (v2-v1)) / 13
            float ys = y1 + ((float)iy * (y2 - y1)) / 13.0f;
            float xs = x1 + ((float)ix * (x2 - x1)) / 13.0f;
            float y0f = floorf(ys);
            float x0f = floorf(xs);
            float wy = ys - y0f;
            float wx = xs - x0f;
            int y0i = min(max((int)y0f, 0), H_DIM - 1);
            int x0i = min(max((int)x0f, 0), W_DIM - 1);
            vld[e] = (ys >= 0.0f) && (ys <= (float)(H_DIM - 1)) &&
                     (xs >= 0.0f) && (xs <= (float)(W_DIM - 1));
            w00[e] = (y0i - yLo) * WC + (x0i - xE);
            wxv[e] = wx; owx[e] = 1.0f - wx;
            wyv[e] = wy; owy[e] = 1.0f - wy;
        }

        const float* wp = &Wnd[(size_t)csub * 8 * WSZ];
        float* op = out + ((size_t)m * C_DIM + cbase + csub * 8) * NPOS + 4 * q;

        #pragma unroll 2
        for (int k = 0; k < 8; ++k) {
            float rv[4];
            #pragma unroll
            for (int e = 0; e < 4; ++e) {
                // taps at constant immediate offsets from w00 -> ds_read2_b32
                float f00 = wp[w00[e]];
                float f01 = wp[w00[e] + 1];
                float f10 = wp[w00[e] + WC];
                float f11 = wp[w00[e] + WC + 1];
                float top = f00 * owx[e] + f01 * wxv[e];
                float bot = f10 * owx[e] + f11 * wxv[e];
                float v   = top * owy[e] + bot * wyv[e];
                rv[e] = vld[e] ? v : 0.0f;
            }
            f32x4 r;
            r.x = rv[0]; r.y = rv[1]; r.z = rv[2]; r.w = rv[3];
            __builtin_nontemporal_store(r, reinterpret_cast<f32x4*>(op));
            wp += WSZ;
            op += NPOS;
        }
    }
}

extern "C" void kernel_launch(void* const* d_in, const int* in_sizes, int n_in,
                              void* d_out, int out_size, void* d_ws, size_t ws_size,
                              hipStream_t stream) {
    const float* fm      = (const float*)d_in[0];
    const float* boxes   = (const float*)d_in[1];
    const int*   box_idx = (const int*)d_in[2];
    float* out = (float*)d_out;

    dim3 block(256);
    dim3 grid(M_BOX * NCHUNK);  // 4096 blocks
    hipLaunchKernelGGL(roi_align_v4, grid, block, 0, stream,
                       fm, boxes, box_idx, out);
}